// Round 1
// 144.931 us; speedup vs baseline: 1.0635x; 1.0635x over previous
//
#include <hip/hip_runtime.h>

#define B_ROWS 2048
#define S_LEN  8192
#define PER_LANE 16
#define WPB 8                          // waves per block (512 threads)
#define CHUNK (64 * PER_LANE)          // 1024 elements per wave
#define NBLOCKS B_ROWS                 // one row per block; 8 waves cover 8192

// ---- compile-time decay constants ----
constexpr double cpowi(double b, int e) { double r = 1.0; for (int i = 0; i < e; ++i) r *= b; return r; }
// flush sub-fp32-normal to zero (this is what makes cross-chunk coupling EXACTLY 0)
constexpr float tof(double x) { return (x < 1.2e-38 && x > -1.2e-38) ? 0.0f : (float)x; }

#define A0f 0.1f
#define A1f 0.3f
#define A2f 0.6f

// Kogge-Stone scan decays: D^(PER_LANE * 2^k), D = (1-alpha)
constexpr float D0_1 = tof(cpowi(0.9, 16)),  D0_2 = tof(cpowi(0.9, 32)),  D0_4 = tof(cpowi(0.9, 64));
constexpr float D0_8 = tof(cpowi(0.9, 128)), D0_16 = tof(cpowi(0.9, 256)), D0_32 = tof(cpowi(0.9, 512));
constexpr float D1_1 = tof(cpowi(0.7, 16)),  D1_2 = tof(cpowi(0.7, 32)),  D1_4 = tof(cpowi(0.7, 64));
constexpr float D1_8 = tof(cpowi(0.7, 128)), D1_16 = tof(cpowi(0.7, 256)), D1_32 = tof(cpowi(0.7, 512));
constexpr float D2_1 = tof(cpowi(0.4, 16)),  D2_2 = tof(cpowi(0.4, 32)),  D2_4 = tof(cpowi(0.4, 64));
constexpr float D2_8 = tof(cpowi(0.4, 128)), D2_16 = tof(cpowi(0.4, 256)), D2_32 = tof(cpowi(0.4, 512));

// log2(1-alpha) for the analytic carry weights (1-a)^(16*lane) = exp2(16*lane*log2(1-a))
#define L2_0 (-0.15200309344504997f)   // log2(0.9)
#define L2_1 (-0.51457317282975830f)   // log2(0.7)
#define L2_2 (-1.32192809488736230f)   // log2(0.4)

// Kogge-Stone inclusive scan for linear recurrence with uniform per-lane decay D:
// v_l = sum_{j<=l} D^(l-j) L_j   (d_k = D^(PER_LANE*2^k)); zero d_k steps fold away.
__device__ __forceinline__ float ema_scan(float v, int lane,
                                          float d1, float d2, float d4,
                                          float d8, float d16, float d32) {
    float u;
    u = __shfl_up(v, 1);  v += (lane >= 1  ? d1  : 0.0f) * u;
    u = __shfl_up(v, 2);  v += (lane >= 2  ? d2  : 0.0f) * u;
    u = __shfl_up(v, 4);  v += (lane >= 4  ? d4  : 0.0f) * u;
    u = __shfl_up(v, 8);  v += (lane >= 8  ? d8  : 0.0f) * u;
    u = __shfl_up(v, 16); v += (lane >= 16 ? d16 : 0.0f) * u;
    u = __shfl_up(v, 32); v += (lane >= 32 ? d32 : 0.0f) * u;
    return v;
}

__device__ __forceinline__ float huber(float pd, float td) {
    float dir = pd * td;
    float se  = fabsf(pd - td);
    float mm  = fmaxf(1.0f - dir, 0.0f);
    float q   = 0.5f * mm * mm;
    return dir < 0.0f ? se : q;
}

__global__ void __launch_bounds__(512) msl_main(const float* __restrict__ pred,
                                                const float* __restrict__ targ,
                                                float* __restrict__ partial) {
    const int lane = threadIdx.x & 63;
    const int wave = threadIdx.x >> 6;
    const float* __restrict__ prow = pred + (size_t)blockIdx.x * S_LEN;
    const float* __restrict__ trow = targ + (size_t)blockIdx.x * S_LEN;
    const int base = wave * CHUNK + lane * PER_LANE;

    float xp[PER_LANE], xt[PER_LANE];
    const float4* p4 = reinterpret_cast<const float4*>(prow + base);
    const float4* t4 = reinterpret_cast<const float4*>(trow + base);
#pragma unroll
    for (int j = 0; j < PER_LANE / 4; ++j) {
        float4 a = p4[j];
        float4 b = t4[j];
        xp[4 * j + 0] = a.x; xp[4 * j + 1] = a.y; xp[4 * j + 2] = a.z; xp[4 * j + 3] = a.w;
        xt[4 * j + 0] = b.x; xt[4 * j + 1] = b.y; xt[4 * j + 2] = b.z; xt[4 * j + 3] = b.w;
    }

    const bool w0   = (wave == 0);
    const bool lz   = (lane == 0);
    const bool head = w0 && lz;   // owns global element 0

    // ---- pass 1: lane-local EMA with zero carry-in (head lane: exact x[0] init;
    // its j=0 update x0 + a*(x0-x0) keeps it exactly x0, matching pe[0]=x[0]) ----
    float Lp0 = head ? xp[0] : 0.0f;
    float Lp1 = head ? xp[0] : 0.0f;
    float Lp2 = head ? xp[0] : 0.0f;
    float Lt0 = head ? xt[0] : 0.0f;
    float Lt1 = head ? xt[0] : 0.0f;
    float Lt2 = head ? xt[0] : 0.0f;
#pragma unroll
    for (int j = 0; j < PER_LANE; ++j) {
        Lp0 += A0f * (xp[j] - Lp0);
        Lp1 += A1f * (xp[j] - Lp1);
        Lp2 += A2f * (xp[j] - Lp2);
        Lt0 += A0f * (xt[j] - Lt0);
        Lt1 += A1f * (xt[j] - Lt1);
        Lt2 += A2f * (xt[j] - Lt2);
    }

    // ---- wave scan: EMA at end of each lane's run, assuming zero chunk carry-in ----
    float vp0 = ema_scan(Lp0, lane, D0_1, D0_2, D0_4, D0_8, D0_16, D0_32);
    float vp1 = ema_scan(Lp1, lane, D1_1, D1_2, D1_4, D1_8, D1_16, D1_32);
    float vp2 = ema_scan(Lp2, lane, D2_1, D2_2, D2_4, D2_8, D2_16, D2_32);
    float vt0 = ema_scan(Lt0, lane, D0_1, D0_2, D0_4, D0_8, D0_16, D0_32);
    float vt1 = ema_scan(Lt1, lane, D1_1, D1_2, D1_4, D1_8, D1_16, D1_32);
    float vt2 = ema_scan(Lt2, lane, D2_1, D2_2, D2_4, D2_8, D2_16, D2_32);

    // ---- publish chunk-exit states. Exit state is carry-in independent:
    // the coupling coefficient (1-a)^1024 underflows to exactly 0.0f. ----
    __shared__ float sex[WPB][6];
    if (lane == 63) {
        sex[wave][0] = vp0; sex[wave][1] = vp1; sex[wave][2] = vp2;
        sex[wave][3] = vt0; sex[wave][4] = vt1; sex[wave][5] = vt2;
    }
    __syncthreads();

    float Cp0 = 0.f, Cp1 = 0.f, Cp2 = 0.f, Ct0 = 0.f, Ct1 = 0.f, Ct2 = 0.f;
    if (wave > 0) {
        Cp0 = sex[wave - 1][0]; Cp1 = sex[wave - 1][1]; Cp2 = sex[wave - 1][2];
        Ct0 = sex[wave - 1][3]; Ct1 = sex[wave - 1][4]; Ct2 = sex[wave - 1][5];
    }

    // analytic carry fold-in: true exclusive carry y_l = v_{l-1} + (1-a)^(16*l) * C
    const float e  = (float)(PER_LANE * lane);
    const float W0 = exp2f(e * L2_0);
    const float W1 = exp2f(e * L2_1);
    const float W2 = exp2f(e * L2_2);

    float up0 = __shfl_up(vp0, 1), up1 = __shfl_up(vp1, 1), up2 = __shfl_up(vp2, 1);
    float ut0 = __shfl_up(vt0, 1), ut1 = __shfl_up(vt1, 1), ut2 = __shfl_up(vt2, 1);

    float yp0 = lz ? (w0 ? xp[0] : Cp0) : fmaf(W0, Cp0, up0);
    float yp1 = lz ? (w0 ? xp[0] : Cp1) : fmaf(W1, Cp1, up1);
    float yp2 = lz ? (w0 ? xp[0] : Cp2) : fmaf(W2, Cp2, up2);
    float yt0 = lz ? (w0 ? xt[0] : Ct0) : fmaf(W0, Ct0, ut0);
    float yt1 = lz ? (w0 ? xt[0] : Ct1) : fmaf(W1, Ct1, ut1);
    float yt2 = lz ? (w0 ? xt[0] : Ct2) : fmaf(W2, Ct2, ut2);

    // ---- pass 2: replay with exact carry, accumulate huber on the deltas ----
    float acc0 = 0.f, acc1 = 0.f, acc2 = 0.f;
    const float skip = head ? 0.0f : 1.0f;  // no loss term for global t=0
#pragma unroll
    for (int j = 0; j < PER_LANE; ++j) {
        float pd0 = A0f * (xp[j] - yp0); yp0 += pd0;
        float td0 = A0f * (xt[j] - yt0); yt0 += td0;
        float pd1 = A1f * (xp[j] - yp1); yp1 += pd1;
        float td1 = A1f * (xt[j] - yt1); yt1 += td1;
        float pd2 = A2f * (xp[j] - yp2); yp2 += pd2;
        float td2 = A2f * (xt[j] - yt2); yt2 += td2;

        float h0 = huber(pd0, td0);
        float h1 = huber(pd1, td1);
        float h2 = huber(pd2, td2);
        if (j == 0) { h0 *= skip; h1 *= skip; h2 *= skip; }
        acc0 += h0; acc1 += h1; acc2 += h2;
    }

    // weight the three scales, reduce across wave, then across the 8 waves (one row)
    float wacc = 0.5f * acc0 + 0.3f * acc1 + 0.2f * acc2;
#pragma unroll
    for (int o = 32; o > 0; o >>= 1) wacc += __shfl_down(wacc, o);

    __shared__ float sred[WPB];
    if (lz) sred[wave] = wacc;
    __syncthreads();
    if (threadIdx.x == 0) {
        float s = 0.f;
#pragma unroll
        for (int i = 0; i < WPB; ++i) s += sred[i];
        partial[blockIdx.x] = s;
    }
}

__global__ void __launch_bounds__(256) msl_reduce(const float* __restrict__ partial,
                                                  float* __restrict__ out) {
    const int tid = threadIdx.x;
    float v = 0.f;
#pragma unroll
    for (int k = 0; k < NBLOCKS / 256; ++k) v += partial[tid + 256 * k];
#pragma unroll
    for (int o = 32; o > 0; o >>= 1) v += __shfl_down(v, o);
    __shared__ float s[4];
    if ((tid & 63) == 0) s[tid >> 6] = v;
    __syncthreads();
    if (tid == 0)
        out[0] = (s[0] + s[1] + s[2] + s[3]) *
                 (float)(1.0 / ((double)(S_LEN - 1) * (double)B_ROWS));
}

extern "C" void kernel_launch(void* const* d_in, const int* in_sizes, int n_in,
                              void* d_out, int out_size, void* d_ws, size_t ws_size,
                              hipStream_t stream) {
    const float* pred = (const float*)d_in[0];
    const float* targ = (const float*)d_in[1];
    float* out = (float*)d_out;
    float* partial = (float*)d_ws;  // 2048 floats = 8 KB

    msl_main<<<NBLOCKS, 512, 0, stream>>>(pred, targ, partial);
    msl_reduce<<<1, 256, 0, stream>>>(partial, out);
}